// Round 9
// baseline (335.184 us; speedup 1.0000x reference)
//
#include <hip/hip_runtime.h>

#define NROWS 8192
#define DDIM  256
#define BM    256
#define BN    128
#define BK    64
#define THREADS 512

typedef __attribute__((ext_vector_type(8))) short bf16x8;
typedef __attribute__((ext_vector_type(4))) float f32x4;

// round-to-nearest-even f32 -> bf16 bits (inputs are finite gaussians; no NaN path)
static __device__ __forceinline__ unsigned short f2bf(float f) {
    unsigned u = __float_as_uint(f);
    u += 0x7fff + ((u >> 16) & 1);
    return (unsigned short)(u >> 16);
}

// Pass 1: f32 -> bf16 conversion + per-row sum of squares.
__global__ __launch_bounds__(256) void rbf_prep_kernel(
    const float* __restrict__ x, const float* __restrict__ y,
    unsigned short* __restrict__ xb, unsigned short* __restrict__ yb,
    float* __restrict__ xsq, float* __restrict__ ysq)
{
    const int lane = threadIdx.x & 63;
    const int wid  = threadIdx.x >> 6;
    int row = blockIdx.x * 4 + wid;            // 0..16383
    const float* src; unsigned short* dst; float* sq; int r;
    if (row < NROWS) { src = x; dst = xb; sq = xsq; r = row; }
    else             { src = y; dst = yb; sq = ysq; r = row - NROWS; }

    const float4 v = ((const float4*)(src + (size_t)r * DDIM))[lane];
    ushort4 b;
    b.x = f2bf(v.x); b.y = f2bf(v.y); b.z = f2bf(v.z); b.w = f2bf(v.w);
    ((ushort4*)(dst + (size_t)r * DDIM))[lane] = b;

    float s = v.x * v.x + v.y * v.y + v.z * v.z + v.w * v.w;
    #pragma unroll
    for (int o = 32; o > 0; o >>= 1) s += __shfl_down(s, o);
    if (lane == 0) sq[r] = s;
}

// Pass 2: C = Xb * Yb^T via bf16 MFMA, epilogue exp(-(xsq + ysq - 2C)).
// 256x128 tile, BK=64, 8 waves 4x2, 512 threads, single-buffered 2-barrier
// K-loop (proven R6 template — persistence regressed: the K-step barrier's
// vmcnt(0) drain serialized prev-tile stores; independent blocks de-burst
// stores naturally). Bigger M-tile = 25% less staging per MFMA and half the
// per-tile prologue exposure, attacking the stage-latency-bound K-loop.
__global__ __launch_bounds__(THREADS) void rbf_gemm_kernel(
    const unsigned short* __restrict__ A,   // 8192 x 256 bf16 (X)
    const unsigned short* __restrict__ B,   // 8192 x 256 bf16 (Y)
    const float* __restrict__ xsq, const float* __restrict__ ysq,
    float* __restrict__ out)
{
    __shared__ unsigned short As[BM * BK];   // 32 KB
    __shared__ unsigned short Bs[BN * BK];   // 16 KB

    const int t    = threadIdx.x;
    const int lane = t & 63;
    const int wid  = t >> 6;            // 0..7
    const int wr   = wid >> 1;          // wave row (0..3) -> 64-row slab of X
    const int wc   = wid & 1;           // wave col (0..1) -> 64-col slab of Y
    const int brow = blockIdx.y * BM;
    const int bcol = blockIdx.x * BN;

    f32x4 acc[4][4] = {};               // [m][n] transposed 16x16 fragments

    const int rr = lane & 15;           // row within fragment (both operands)
    const int kq = lane >> 4;           // k-quarter
    const int cl = lane & 15;
    const int rq = lane >> 4;

    for (int kt = 0; kt < DDIM; kt += BK) {
        // stage A-tile [256][64]: 2048 16B-chunks, 4 per thread
        #pragma unroll
        for (int i = 0; i < 4; ++i) {
            const int idx = (i * THREADS + t) * 8;
            const int r   = idx >> 6;
            const int c   = idx & 63;
            __builtin_amdgcn_global_load_lds(
                (const __attribute__((address_space(1))) unsigned int*)(A + (size_t)(brow + r) * DDIM + kt + c),
                (__attribute__((address_space(3))) unsigned int*)(As + idx), 16, 0, 0);
        }
        // stage B-tile [128][64]: 1024 chunks, 2 per thread
        #pragma unroll
        for (int i = 0; i < 2; ++i) {
            const int idx = (i * THREADS + t) * 8;
            const int r   = idx >> 6;
            const int c   = idx & 63;
            __builtin_amdgcn_global_load_lds(
                (const __attribute__((address_space(1))) unsigned int*)(B + (size_t)(bcol + r) * DDIM + kt + c),
                (__attribute__((address_space(3))) unsigned int*)(Bs + idx), 16, 0, 0);
        }
        __syncthreads();

        #pragma unroll
        for (int ks = 0; ks < 2; ++ks) {
            bf16x8 a[4], b[4];
            const int ko = ks * 32 + kq * 8;
            #pragma unroll
            for (int m = 0; m < 4; ++m)
                a[m] = *(const bf16x8*)(As + (wr * 64 + m * 16 + rr) * BK + ko);
            #pragma unroll
            for (int n = 0; n < 4; ++n)
                b[n] = *(const bf16x8*)(Bs + (wc * 64 + n * 16 + rr) * BK + ko);
            #pragma unroll
            for (int m = 0; m < 4; ++m)
                #pragma unroll
                for (int n = 0; n < 4; ++n)
                    acc[m][n] = __builtin_amdgcn_mfma_f32_16x16x32_bf16(b[n], a[m], acc[m][n], 0, 0, 0);
        }
        __syncthreads();
    }

    // epilogue: swapped-operand fragment => lane's X row = lane&15,
    // Y cols = (lane>>4)*4 + {0..3} -> nontemporal f32x4 stores
    #pragma unroll
    for (int m = 0; m < 4; ++m) {
        const int row = brow + wr * 64 + m * 16 + cl;
        const float xsv = xsq[row];
        float* orow = out + (size_t)row * NROWS;
        #pragma unroll
        for (int n = 0; n < 4; ++n) {
            const int col = bcol + wc * 64 + n * 16 + rq * 4;
            const float4 ysv = *(const float4*)(ysq + col);
            f32x4 o;
            o[0] = __expf(-fmaxf(xsv + ysv.x - 2.0f * acc[m][n][0], 0.0f));
            o[1] = __expf(-fmaxf(xsv + ysv.y - 2.0f * acc[m][n][1], 0.0f));
            o[2] = __expf(-fmaxf(xsv + ysv.z - 2.0f * acc[m][n][2], 0.0f));
            o[3] = __expf(-fmaxf(xsv + ysv.w - 2.0f * acc[m][n][3], 0.0f));
            __builtin_nontemporal_store(o, (f32x4*)(orow + col));
        }
    }
}

extern "C" void kernel_launch(void* const* d_in, const int* in_sizes, int n_in,
                              void* d_out, int out_size, void* d_ws, size_t ws_size,
                              hipStream_t stream) {
    const float* x = (const float*)d_in[0];
    const float* y = (const float*)d_in[1];
    float* out = (float*)d_out;

    // ws layout: xb (4 MiB) | yb (4 MiB) | xsq (32 KiB) | ysq (32 KiB)
    unsigned short* xb = (unsigned short*)d_ws;
    unsigned short* yb = xb + (size_t)NROWS * DDIM;
    float* xsq = (float*)(yb + (size_t)NROWS * DDIM);
    float* ysq = xsq + NROWS;

    rbf_prep_kernel<<<dim3((2 * NROWS) / 4), 256, 0, stream>>>(x, y, xb, yb, xsq, ysq);
    rbf_gemm_kernel<<<dim3(NROWS / BN, NROWS / BM), THREADS, 0, stream>>>(xb, yb, xsq, ysq, out);
}

// Round 11
// 302.115 us; speedup vs baseline: 1.1095x; 1.1095x over previous
//
#include <hip/hip_runtime.h>

#define NROWS 8192
#define DDIM  256
#define BM    128
#define BN    128
#define BK    64

typedef __attribute__((ext_vector_type(8))) short bf16x8;
typedef __attribute__((ext_vector_type(4))) float f32x4;

// round-to-nearest-even f32 -> bf16 bits (inputs are finite gaussians; no NaN path)
static __device__ __forceinline__ unsigned short f2bf(float f) {
    unsigned u = __float_as_uint(f);
    u += 0x7fff + ((u >> 16) & 1);
    return (unsigned short)(u >> 16);
}

// Pass 1: f32 -> bf16 conversion + per-row sum of squares.
__global__ __launch_bounds__(256) void rbf_prep_kernel(
    const float* __restrict__ x, const float* __restrict__ y,
    unsigned short* __restrict__ xb, unsigned short* __restrict__ yb,
    float* __restrict__ xsq, float* __restrict__ ysq)
{
    const int lane = threadIdx.x & 63;
    const int wid  = threadIdx.x >> 6;
    int row = blockIdx.x * 4 + wid;            // 0..16383
    const float* src; unsigned short* dst; float* sq; int r;
    if (row < NROWS) { src = x; dst = xb; sq = xsq; r = row; }
    else             { src = y; dst = yb; sq = ysq; r = row - NROWS; }

    const float4 v = ((const float4*)(src + (size_t)r * DDIM))[lane];
    ushort4 b;
    b.x = f2bf(v.x); b.y = f2bf(v.y); b.z = f2bf(v.z); b.w = f2bf(v.w);
    ((ushort4*)(dst + (size_t)r * DDIM))[lane] = b;

    float s = v.x * v.x + v.y * v.y + v.z * v.z + v.w * v.w;
    #pragma unroll
    for (int o = 32; o > 0; o >>= 1) s += __shfl_down(s, o);
    if (lane == 0) sq[r] = s;
}

// Pass 2: R6 structure (128x128, 4 waves 2x2, single-buffer, nt stores)
// + T2 LDS XOR-swizzle, both-sides (rule #21):
//   - LDS dest of global_load_lds stays LINEAR (HW requirement),
//   - global SOURCE column pre-swizzled: chunk c -> c ^ ((row&7)<<3) elems,
//   - ds_read address swizzled with the same XOR.
// Rationale: row stride 128B => lanes of one kq-group read 16 rows at the
// same 16B column = 16-way bank conflict (~16 LDS cyc/instr vs 8 floor);
// chip-wide ds_read time ~85us == measured GEMM time. Swizzle spreads the
// wave across all 8 bank-quads -> b128 structural floor.
__global__ __launch_bounds__(256) void rbf_gemm_kernel(
    const unsigned short* __restrict__ A,   // 8192 x 256 bf16 (X)
    const unsigned short* __restrict__ B,   // 8192 x 256 bf16 (Y)
    const float* __restrict__ xsq, const float* __restrict__ ysq,
    float* __restrict__ out)
{
    __shared__ unsigned short As[BM * BK];
    __shared__ unsigned short Bs[BN * BK];

    const int t    = threadIdx.x;
    const int lane = t & 63;
    const int wid  = t >> 6;
    const int wr   = wid >> 1;          // wave row (0..1) -> 64-row slab of X
    const int wc   = wid & 1;           // wave col (0..1) -> 64-col slab of Y
    const int brow = blockIdx.y * BM;
    const int bcol = blockIdx.x * BN;

    f32x4 acc[4][4] = {};               // [m][n] transposed 16x16 fragments

    const int rr = lane & 15;           // row within fragment (both operands)
    const int kq = lane >> 4;           // k-quarter
    const int cl = lane & 15;
    const int rq = lane >> 4;

    for (int kt = 0; kt < DDIM; kt += BK) {
        #pragma unroll
        for (int i = 0; i < 4; ++i) {
            const int idx = (i * 256 + t) * 8;      // element index in tile (16B-chunk aligned)
            const int r   = idx >> 6;               // tile row
            const int c   = idx & 63;               // linear chunk col (elements)
            const int cs  = c ^ ((r & 7) << 3);     // inverse-swizzled SOURCE col
            __builtin_amdgcn_global_load_lds(
                (const __attribute__((address_space(1))) unsigned int*)(A + (size_t)(brow + r) * DDIM + kt + cs),
                (__attribute__((address_space(3))) unsigned int*)(As + idx), 16, 0, 0);
            __builtin_amdgcn_global_load_lds(
                (const __attribute__((address_space(1))) unsigned int*)(B + (size_t)(bcol + r) * DDIM + kt + cs),
                (__attribute__((address_space(3))) unsigned int*)(Bs + idx), 16, 0, 0);
        }
        __syncthreads();

        #pragma unroll
        for (int ks = 0; ks < 2; ++ks) {
            bf16x8 a[4], b[4];
            const int ko = ks * 32 + kq * 8;        // logical k-offset (elements)
            const int sw = (rr & 7) << 3;           // row's swizzle bits
            #pragma unroll
            for (int m = 0; m < 4; ++m)
                a[m] = *(const bf16x8*)(As + (wr * 64 + m * 16 + rr) * BK + (ko ^ sw));
            #pragma unroll
            for (int n = 0; n < 4; ++n)
                b[n] = *(const bf16x8*)(Bs + (wc * 64 + n * 16 + rr) * BK + (ko ^ sw));
            #pragma unroll
            for (int m = 0; m < 4; ++m)
                #pragma unroll
                for (int n = 0; n < 4; ++n)
                    acc[m][n] = __builtin_amdgcn_mfma_f32_16x16x32_bf16(b[n], a[m], acc[m][n], 0, 0, 0);
        }
        __syncthreads();
    }

    // epilogue: swapped-operand fragment => lane's X row = lane&15,
    // Y cols = (lane>>4)*4 + {0..3} -> nontemporal f32x4 stores
    #pragma unroll
    for (int m = 0; m < 4; ++m) {
        const int row = brow + wr * 64 + m * 16 + cl;
        const float xsv = xsq[row];
        float* orow = out + (size_t)row * NROWS;
        #pragma unroll
        for (int n = 0; n < 4; ++n) {
            const int col = bcol + wc * 64 + n * 16 + rq * 4;
            const float4 ysv = *(const float4*)(ysq + col);
            f32x4 o;
            o[0] = __expf(-fmaxf(xsv + ysv.x - 2.0f * acc[m][n][0], 0.0f));
            o[1] = __expf(-fmaxf(xsv + ysv.y - 2.0f * acc[m][n][1], 0.0f));
            o[2] = __expf(-fmaxf(xsv + ysv.z - 2.0f * acc[m][n][2], 0.0f));
            o[3] = __expf(-fmaxf(xsv + ysv.w - 2.0f * acc[m][n][3], 0.0f));
            __builtin_nontemporal_store(o, (f32x4*)(orow + col));
        }
    }
}

extern "C" void kernel_launch(void* const* d_in, const int* in_sizes, int n_in,
                              void* d_out, int out_size, void* d_ws, size_t ws_size,
                              hipStream_t stream) {
    const float* x = (const float*)d_in[0];
    const float* y = (const float*)d_in[1];
    float* out = (float*)d_out;

    // ws layout: xb (4 MiB) | yb (4 MiB) | xsq (32 KiB) | ysq (32 KiB)
    unsigned short* xb = (unsigned short*)d_ws;
    unsigned short* yb = xb + (size_t)NROWS * DDIM;
    float* xsq = (float*)(yb + (size_t)NROWS * DDIM);
    float* ysq = xsq + NROWS;

    rbf_prep_kernel<<<dim3((2 * NROWS) / 4), 256, 0, stream>>>(x, y, xb, yb, xsq, ysq);
    rbf_gemm_kernel<<<dim3(NROWS / BN, NROWS / BM), 256, 0, stream>>>(xb, yb, xsq, ysq, out);
}